// Round 14
// baseline (555.912 us; speedup 1.0000x reference)
//
#include <hip/hip_runtime.h>

typedef unsigned short u16;
typedef unsigned int   u32;
typedef short bf16x8 __attribute__((ext_vector_type(8)));
typedef float f32x4  __attribute__((ext_vector_type(4)));

__device__ __forceinline__ float b2f(u16 u){ return __uint_as_float(((u32)u) << 16); }
__device__ __forceinline__ u16 f2bf(float f){
  u32 u = __float_as_uint(f);
  return (u16)((u + 0x7fffu + ((u >> 16) & 1u)) >> 16);  // RNE
}

// async global->LDS, 16B per lane, wave-uniform LDS base + lane*16
__device__ __forceinline__ void gload16(const u16* g, u16* l) {
  __builtin_amdgcn_global_load_lds(
      (const __attribute__((address_space(1))) unsigned int*)(g),
      (__attribute__((address_space(3))) unsigned int*)(l), 16, 0, 0);
}

// ---------------------------------------------------------------------------
// Transpose+cast four fp32 1536x1536 weights into bf16 WT[n][k]=W[k][n].
// ---------------------------------------------------------------------------
__global__ __launch_bounds__(256) void transpose4(
    const float* __restrict__ Wq, const float* __restrict__ Wk,
    const float* __restrict__ Wv, const float* __restrict__ Wo, u16* __restrict__ wt)
{
  __shared__ float tile[32][33];
  const float* src = blockIdx.z == 0 ? Wq : blockIdx.z == 1 ? Wk : blockIdx.z == 2 ? Wv : Wo;
  u16* dst = wt + (size_t)blockIdx.z * 1536 * 1536;
  const int bx = blockIdx.x * 32, by = blockIdx.y * 32;
  const int tx = threadIdx.x, ty = threadIdx.y;  // 32 x 8
#pragma unroll
  for (int i = 0; i < 32; i += 8)
    tile[ty + i][tx] = src[(size_t)(by + ty + i) * 1536 + bx + tx];
  __syncthreads();
#pragma unroll
  for (int i = 0; i < 32; i += 8)
    dst[(size_t)(bx + ty + i) * 1536 + by + tx] = f2bf(tile[tx][ty + i]);
}

// fp32 -> bf16 cast for x.
__global__ __launch_bounds__(256) void cast_f32_bf16(
    const float* __restrict__ src, u16* __restrict__ dst, int n4)
{
  int i = blockIdx.x * 256 + threadIdx.x;
  if (i < n4) {
    float4 f = ((const float4*)src)[i];
    ushort4 o;
    o.x = f2bf(f.x); o.y = f2bf(f.y); o.z = f2bf(f.z); o.w = f2bf(f.w);
    ((ushort4*)dst)[i] = o;
  }
}

// ---------------------------------------------------------------------------
// GEMM core: C = A @ BT^T + bias. bf16 MFMA, fp32 acc.
// 128x128 tile, 4 waves 2x2, 4x4 mfma 16x16x32.  [frozen r4 K-loop]
// MODE 0: bf16 C[row][1536]; MODE 1: f32 C[row][1536];
// MODE 2 (r14): bf16 C^T[col][Lpad]+row — V written pre-transposed for attn,
// eliminating the separate transpose_v pass (vraw round-trip + dispatch).
// Per lane the 4 acc rows are contiguous in transposed layout -> ushort4
// stores; 4 quads/wave form 32B segments per vtb row. Pad rows [M,Lpad)
// zeroed by hipMemsetAsync upstream.
// ---------------------------------------------------------------------------
template<int MODE>
__device__ __forceinline__ void gemm_core(
    const u16* __restrict__ A, const u16* __restrict__ BT,
    const float* __restrict__ bias, void* __restrict__ Cv, int M,
    int m0, int n0, int Lpad)
{
  __shared__ u16 As[2][128][32];
  __shared__ u16 Bs[2][128][32];
  const int tid = threadIdx.x;
  const int wave = tid >> 6, lane = tid & 63;
  const int wm = (wave & 1) * 64, wn = (wave >> 1) * 64;
  const int l16 = lane & 15, quad = lane >> 4;

  // per-lane staging sources (ks = 0); each wave owns a 32-row strip.
  const int srow = lane >> 2, scol = (lane & 3) * 8;
  const u16* ap0 = A  + (size_t)(m0 + wave * 32 + srow) * 1536 + scol;
  const u16* ap1 = ap0 + (size_t)16 * 1536;
  const u16* bp0 = BT + (size_t)(n0 + wave * 32 + srow) * 1536 + scol;
  const u16* bp1 = bp0 + (size_t)16 * 1536;

#define STAGE_GEMM(curb) do { \
    gload16(ap0, &As[curb][wave * 32][0]); \
    gload16(ap1, &As[curb][wave * 32 + 16][0]); \
    gload16(bp0, &Bs[curb][wave * 32][0]); \
    gload16(bp1, &Bs[curb][wave * 32 + 16][0]); \
    ap0 += 32; ap1 += 32; bp0 += 32; bp1 += 32; } while (0)

  f32x4 acc[4][4] = {};
  STAGE_GEMM(0);
  for (int ks = 0; ks < 48; ks++) {
    const int cur = ks & 1;
    if (ks + 1 < 48) {
      STAGE_GEMM(cur ^ 1);
      asm volatile("s_waitcnt vmcnt(4)" ::: "memory");   // ks's 4 loads landed
    } else {
      asm volatile("s_waitcnt vmcnt(0)" ::: "memory");
    }
    __builtin_amdgcn_s_barrier();          // all waves: tile ks visible
    __builtin_amdgcn_sched_barrier(0);     // don't hoist ds_reads above barrier
    bf16x8 af[4], bfr[4];
#pragma unroll
    for (int mt = 0; mt < 4; mt++) af[mt] = *(const bf16x8*)&As[cur][wm + mt * 16 + l16][quad * 8];
#pragma unroll
    for (int nt = 0; nt < 4; nt++) bfr[nt] = *(const bf16x8*)&Bs[cur][wn + nt * 16 + l16][quad * 8];
#pragma unroll
    for (int mt = 0; mt < 4; mt++)
#pragma unroll
      for (int nt = 0; nt < 4; nt++)
        acc[mt][nt] = __builtin_amdgcn_mfma_f32_16x16x32_bf16(af[mt], bfr[nt], acc[mt][nt], 0, 0, 0);
    __builtin_amdgcn_s_barrier();          // all reads of buf[cur] done
  }
#undef STAGE_GEMM

#pragma unroll
  for (int nt = 0; nt < 4; nt++) {
    int col = n0 + wn + nt * 16 + l16;
    float bv = bias[col];
#pragma unroll
    for (int mt = 0; mt < 4; mt++) {
      int rowb = m0 + wm + mt * 16 + quad * 4;
      if (MODE == 2) {
        u16 h[4];
#pragma unroll
        for (int r = 0; r < 4; r++) h[r] = f2bf(acc[mt][nt][r] + bv);
        u16* dst = (u16*)Cv + (size_t)col * Lpad + rowb;
        if (rowb + 3 < M) {
          ushort4 w4 = { h[0], h[1], h[2], h[3] };
          *(ushort4*)dst = w4;
        } else {
#pragma unroll
          for (int r = 0; r < 4; r++) if (rowb + r < M) dst[r] = h[r];
        }
      } else {
#pragma unroll
        for (int r = 0; r < 4; r++) {
          int row = rowb + r;
          if (row < M) {
            float val = acc[mt][nt][r] + bv;
            if (MODE == 1) ((float*)Cv)[(size_t)row * 1536 + col] = val;
            else           ((u16*)Cv)[(size_t)row * 1536 + col] = f2bf(val);
          }
        }
      }
    }
  }
}

// Fused Q/K/V projection: blockIdx.z selects weight/bias/output.
// z==2 (V) writes transposed into vtb (MODE 2); z==0/1 write row-major.
__global__ __launch_bounds__(256) void gemm_qkv(
    const u16* __restrict__ A, const u16* __restrict__ wt,
    const float* __restrict__ bq, const float* __restrict__ bk, const float* __restrict__ bv,
    u16* __restrict__ qraw, u16* __restrict__ kraw, u16* __restrict__ vtb,
    int M, size_t SZW, int Lpad)
{
  const int z = blockIdx.z;
  const u16* BT = wt + (size_t)z * SZW;
  if (z == 2) {
    gemm_core<2>(A, BT, bv, vtb, M, blockIdx.x * 128, blockIdx.y * 128, Lpad);
  } else {
    const float* bias = z == 0 ? bq : bk;
    u16* C = z == 0 ? qraw : kraw;
    gemm_core<0>(A, BT, bias, C, M, blockIdx.x * 128, blockIdx.y * 128, Lpad);
  }
}

__global__ __launch_bounds__(256) void gemm_out(
    const u16* __restrict__ A, const u16* __restrict__ BT,
    const float* __restrict__ bias, float* __restrict__ C, int M)
{
  gemm_core<1>(A, BT, bias, C, M, blockIdx.x * 128, blockIdx.y * 128, 0);
}

// ---------------------------------------------------------------------------
// In-place RMSNorm (dim 1536) + per-head RoPE on bf16 q/k; fp32 gains/freqs.
// r10: q additionally pre-scaled by SC = (1/sqrt(128))*log2(e) — qraw's only
// consumer is attn's Q (rope is linear, so rot(SC*q) = SC*rot(q)).
// ---------------------------------------------------------------------------
__global__ __launch_bounds__(256) void rmsrope(
    u16* __restrict__ qb, u16* __restrict__ kb,
    const float* __restrict__ gq, const float* __restrict__ gk,
    const float* __restrict__ freqs, const int* __restrict__ gsz)
{
  const int s = blockIdx.x, tid = threadIdx.x;
  const size_t base = (size_t)s * 1536;
  float qv[6], kv[6];
  float sq = 0.f, sk = 0.f;
#pragma unroll
  for (int i = 0; i < 6; i++) {
    float a = b2f(qb[base + tid * 6 + i]); qv[i] = a; sq += a * a;
    float b = b2f(kb[base + tid * 6 + i]); kv[i] = b; sk += b * b;
  }
#pragma unroll
  for (int d2 = 1; d2 < 64; d2 <<= 1) { sq += __shfl_xor(sq, d2); sk += __shfl_xor(sk, d2); }
  __shared__ float red[8];
  const int wave = tid >> 6, lane = tid & 63;
  if (lane == 0) { red[wave] = sq; red[4 + wave] = sk; }
  __syncthreads();
  sq = red[0] + red[1] + red[2] + red[3];
  sk = red[4] + red[5] + red[6] + red[7];
  const float rq = rsqrtf(sq * (1.f / 1536.f) + 1e-6f) * 0.12752551286084934f;  // * SC
  const float rk = rsqrtf(sk * (1.f / 1536.f) + 1e-6f);
  const int F = gsz[0], H = gsz[1], W = gsz[2];
  const int sl = F * H * W;
  const bool rope = s < sl;
  int pf = 0, ph = 0, pw = 0;
  if (rope) { pf = s / (H * W); int rr = s - pf * (H * W); ph = rr / W; pw = rr - ph * W; }
#pragma unroll
  for (int pp = 0; pp < 3; pp++) {
    const int j0 = tid * 6 + pp * 2;
    float qre = qv[pp * 2]     * rq * gq[j0];
    float qim = qv[pp * 2 + 1] * rq * gq[j0 + 1];
    float kre = kv[pp * 2]     * rk * gk[j0];
    float kim = kv[pp * 2 + 1] * rk * gk[j0 + 1];
    if (rope) {
      const int ti = (j0 & 127) >> 1;
      const int pos = ti < 22 ? pf : (ti < 43 ? ph : pw);
      const float ang = freqs[pos * 64 + ti];
      const float cs = cosf(ang), sn = sinf(ang);
      float t1 = qre * cs - qim * sn; qim = qre * sn + qim * cs; qre = t1;
      float t2 = kre * cs - kim * sn; kim = kre * sn + kim * cs; kre = t2;
    }
    qb[base + j0] = f2bf(qre); qb[base + j0 + 1] = f2bf(qim);
    kb[base + j0] = f2bf(kre); kb[base + j0 + 1] = f2bf(kim);
  }
}

// ---------------------------------------------------------------------------
// MFMA flash attention, 64-key tiles, register-double-buffered K/V staging.
// Block = 4 waves = 128 q rows (32/wave, two 16-row fragments), one head.
// Frozen at r13 (within noise of r8's proven 264.6us; VALU diet exhausted —
// latency-bound on the QK->softmax->PV dependent chain at 2 waves/SIMD).
// ---------------------------------------------------------------------------
__global__ __launch_bounds__(256, 2) void attn_mfma(
    const u16* __restrict__ q, const u16* __restrict__ k, const u16* __restrict__ vt,
    u16* __restrict__ o, const int* __restrict__ seq_lens, int L, int Lpad)
{
  __shared__ u16 Ks[64][136];    // K rows [key][d], pad 8
  __shared__ u16 Vs[128][72];    // V^T [d][key], pad 8
  __shared__ u16 Pl[4][32][72];  // per-wave P [q][key], pad 8
  const int tid = threadIdx.x, wave = tid >> 6, lane = tid & 63;
  const int l16 = lane & 15, quad = lane >> 4;
  const int h = blockIdx.y;
  const int seqlen = seq_lens[0];
  const int q0 = blockIdx.x * 128 + wave * 32;

  // staging coordinates (per thread, fixed)
  int krow[4], kcol[4], vd[4], voct[4];
#pragma unroll
  for (int i = 0; i < 4; i++) {
    int slot = tid + i * 256;
    krow[i] = slot >> 4; kcol[i] = (slot & 15) * 8;
    vd[i]   = slot >> 3; voct[i] = (slot & 7) * 8;
  }
  const u16* kp  = k + h * 128;
  const u16* vtp = vt + (size_t)h * 128 * Lpad;
  // incrementing prefetch pointers (advance by one 64-key tile per iteration)
  const u16* kptr[4]; const u16* vptr[4];
#pragma unroll
  for (int i = 0; i < 4; i++) {
    kptr[i] = kp + (size_t)krow[i] * 1536 + kcol[i];
    vptr[i] = vtp + (size_t)vd[i] * Lpad + voct[i];
  }

  // Q fragments for both 16-row groups (already scaled by SC in rmsrope)
  bf16x8 Qf[2][4];
#pragma unroll
  for (int qg = 0; qg < 2; qg++) {
    int qr = q0 + qg * 16 + l16;
#pragma unroll
    for (int ds = 0; ds < 4; ds++) {
      bf16x8 z = {0, 0, 0, 0, 0, 0, 0, 0};
      if (qr < L)
        z = *(const bf16x8*)(q + (size_t)qr * 1536 + h * 128 + ds * 32 + quad * 8);
      Qf[qg][ds] = z;
    }
  }
  // constant ones B-fragment: n-col 0 (lanes with l16==0) = bf16 1.0
  bf16x8 ovf = {0, 0, 0, 0, 0, 0, 0, 0};
  if (l16 == 0) {
#pragma unroll
    for (int j = 0; j < 8; j++) ovf[j] = (short)0x3F80;
  }
  f32x4 accO[2][8] = {};
  f32x4 accL[2] = {};
  float m_i[2] = {-1e30f, -1e30f};

  const int ntile = (seqlen + 63) >> 6;
  bf16x8 kpre[4], vpre[4];
  // prefetch tile 0 (unguarded: OOR rows land in adjacent allocated buffer)
#pragma unroll
  for (int i = 0; i < 4; i++) {
    kpre[i] = *(const bf16x8*)kptr[i];
    vpre[i] = *(const bf16x8*)vptr[i];
  }

  for (int t = 0; t < ntile; t++) {
    const int kb = t * 64;
    // readers-done barrier: raw s_barrier — no vmcnt/lgkm drain needed (all
    // ds_reads of tile t-1 were consumed by MFMAs). sched_barrier fences keep
    // the staging ds_writes below it (rule #18).
    __builtin_amdgcn_sched_barrier(0);
    __builtin_amdgcn_s_barrier();
    __builtin_amdgcn_sched_barrier(0);
#pragma unroll
    for (int i = 0; i < 4; i++) {
      *(bf16x8*)&Ks[krow[i]][kcol[i]] = kpre[i];
      *(bf16x8*)&Vs[vd[i]][voct[i]]   = vpre[i];
    }
    __syncthreads();   // staging visible (full drain: ds_writes must land)
    if (t + 1 < ntile) {
#pragma unroll
      for (int i = 0; i < 4; i++) {
        kptr[i] += (size_t)64 * 1536;
        vptr[i] += 64;
        kpre[i] = *(const bf16x8*)kptr[i];
        vpre[i] = *(const bf16x8*)vptr[i];
      }
    }

    // S^T: four 16(key)x16(q) tiles over d=128, both q-groups per K fragment
    const bool full = (kb + 64 <= seqlen);
    float sv[2][16];
    float tmax[2] = {-1e30f, -1e30f};
    __builtin_amdgcn_s_setprio(1);
#pragma unroll
    for (int kt = 0; kt < 4; kt++) {
      f32x4 a0 = {0.f, 0.f, 0.f, 0.f};
      f32x4 a1 = {0.f, 0.f, 0.f, 0.f};
#pragma unroll
      for (int ds = 0; ds < 4; ds++) {
        bf16x8 kf = *(const bf16x8*)&Ks[kt * 16 + l16][ds * 32 + quad * 8];
        a0 = __builtin_amdgcn_mfma_f32_16x16x32_bf16(kf, Qf[0][ds], a0, 0, 0, 0);
        a1 = __builtin_amdgcn_mfma_f32_16x16x32_bf16(kf, Qf[1][ds], a1, 0, 0, 0);
      }
      if (full) {
#pragma unroll
        for (int r = 0; r < 4; r++) { sv[0][kt * 4 + r] = a0[r]; sv[1][kt * 4 + r] = a1[r]; }
        // tree max (max3-fusable): 2 ops to reduce 4, 1 to accumulate
        tmax[0] = fmaxf(tmax[0], fmaxf(fmaxf(a0[0], a0[1]), fmaxf(a0[2], a0[3])));
        tmax[1] = fmaxf(tmax[1], fmaxf(fmaxf(a1[0], a1[1]), fmaxf(a1[2], a1[3])));
      } else {
#pragma unroll
        for (int r = 0; r < 4; r++) {
          int key = kb + kt * 16 + quad * 4 + r;
          float s0 = (key < seqlen) ? a0[r] : -1e30f;
          float s1 = (key < seqlen) ? a1[r] : -1e30f;
          sv[0][kt * 4 + r] = s0; tmax[0] = fmaxf(tmax[0], s0);
          sv[1][kt * 4 + r] = s1; tmax[1] = fmaxf(tmax[1], s1);
        }
      }
    }
    __builtin_amdgcn_s_setprio(0);
    bool resc[2];
    float alpha[2] = {1.f, 1.f};
#pragma unroll
    for (int qg = 0; qg < 2; qg++) {
      float tm = tmax[qg];
      tm = fmaxf(tm, __shfl_xor(tm, 16));
      tm = fmaxf(tm, __shfl_xor(tm, 32));
      resc[qg] = !__all(tm - m_i[qg] <= 8.f);
      float mnew = m_i[qg];
      if (resc[qg]) {                       // wave-uniform branch
        mnew = fmaxf(m_i[qg], tm);
        alpha[qg] = exp2f(m_i[qg] - mnew);
      }
      // pair-pack truncated-bf16 P: (hi16(pb)<<16)|hi16(pa) per pair
      u32 pw[8];
#pragma unroll
      for (int i2 = 0; i2 < 8; i2++) {
        float pa = exp2f(sv[qg][i2 * 2]     - mnew);
        float pb = exp2f(sv[qg][i2 * 2 + 1] - mnew);
        pw[i2] = (__float_as_uint(pb) & 0xffff0000u) | (__float_as_uint(pa) >> 16);
      }
      m_i[qg] = mnew;
#pragma unroll
      for (int kt = 0; kt < 4; kt++) {
        uint2 w2 = { pw[kt * 2], pw[kt * 2 + 1] };
        *(uint2*)&Pl[wave][qg * 16 + l16][kt * 16 + quad * 4] = w2;
      }
    }
#pragma unroll
    for (int qg = 0; qg < 2; qg++) {
      if (resc[qg]) {                       // wave-uniform: usually skipped
        float ar[4];
#pragma unroll
        for (int r = 0; r < 4; r++) ar[r] = __shfl(alpha[qg], quad * 4 + r);
#pragma unroll
        for (int dt = 0; dt < 8; dt++)
#pragma unroll
          for (int r = 0; r < 4; r++) accO[qg][dt][r] *= ar[r];
#pragma unroll
        for (int r = 0; r < 4; r++) accL[qg][r] *= ar[r];
      }
    }
    bf16x8 pf00 = *(const bf16x8*)&Pl[wave][l16][quad * 8];
    bf16x8 pf01 = *(const bf16x8*)&Pl[wave][l16][32 + quad * 8];
    bf16x8 pf10 = *(const bf16x8*)&Pl[wave][16 + l16][quad * 8];
    bf16x8 pf11 = *(const bf16x8*)&Pl[wave][16 + l16][32 + quad * 8];
    __builtin_amdgcn_s_setprio(1);
#pragma unroll
    for (int dt = 0; dt < 8; dt++) {
      bf16x8 vf0 = *(const bf16x8*)&Vs[dt * 16 + l16][quad * 8];
      bf16x8 vf1 = *(const bf16x8*)&Vs[dt * 16 + l16][32 + quad * 8];
      accO[0][dt] = __builtin_amdgcn_mfma_f32_16x16x32_bf16(pf00, vf0, accO[0][dt], 0, 0, 0);
      accO[0][dt] = __builtin_amdgcn_mfma_f32_16x16x32_bf16(pf01, vf1, accO[0][dt], 0, 0, 0);
      accO[1][dt] = __builtin_amdgcn_mfma_f32_16x16x32_bf16(pf10, vf0, accO[1][dt], 0, 0, 0);
      accO[1][dt] = __builtin_amdgcn_mfma_f32_16x16x32_bf16(pf11, vf1, accO[1][dt], 0, 0, 0);
    }
    // l accumulation: D[q][0] += sum_k P[q][k] * 1  (n-col 0 only)
    accL[0] = __builtin_amdgcn_mfma_f32_16x16x32_bf16(pf00, ovf, accL[0], 0, 0, 0);
    accL[0] = __builtin_amdgcn_mfma_f32_16x16x32_bf16(pf01, ovf, accL[0], 0, 0, 0);
    accL[1] = __builtin_amdgcn_mfma_f32_16x16x32_bf16(pf10, ovf, accL[1], 0, 0, 0);
    accL[1] = __builtin_amdgcn_mfma_f32_16x16x32_bf16(pf11, ovf, accL[1], 0, 0, 0);
    __builtin_amdgcn_s_setprio(0);
  }
  // epilogue: l(q=quad*4+r) = accL[qg][r] at lane l16==0 of this quad
#pragma unroll
  for (int qg = 0; qg < 2; qg++) {
    float linv[4];
#pragma unroll
    for (int r = 0; r < 4; r++) linv[r] = 1.f / __shfl(accL[qg][r], quad << 4);
#pragma unroll
    for (int r = 0; r < 4; r++) {
      int qr = q0 + qg * 16 + quad * 4 + r;
      if (qr < L) {
#pragma unroll
        for (int dt = 0; dt < 8; dt++)
          o[(size_t)qr * 1536 + h * 128 + dt * 16 + l16] = f2bf(accO[qg][dt][r] * linv[r]);
      }
    }
  }
}

// ---------------------------------------------------------------------------
extern "C" void kernel_launch(void* const* d_in, const int* in_sizes, int n_in,
                              void* d_out, int out_size, void* d_ws, size_t ws_size,
                              hipStream_t stream) {
  const float* x      = (const float*)d_in[0];
  const int* seq_lens = (const int*)d_in[1];
  const int* gsz      = (const int*)d_in[2];
  const float* freqs  = (const float*)d_in[3];
  const float* Wq     = (const float*)d_in[4];
  const float* bq     = (const float*)d_in[5];
  const float* Wk     = (const float*)d_in[6];
  const float* bk     = (const float*)d_in[7];
  const float* Wv     = (const float*)d_in[8];
  const float* bv     = (const float*)d_in[9];
  const float* Wo     = (const float*)d_in[10];
  const float* bo     = (const float*)d_in[11];
  const float* gq     = (const float*)d_in[12];
  const float* gk     = (const float*)d_in[13];
  float* out = (float*)d_out;   // fp32 output (proven round 5)

  const int DIM = 1536;
  const int L = in_sizes[0] / DIM;              // 5000
  const int Lpad = ((L + 63) / 64) * 64;        // 5056
  const size_t SZW = (size_t)DIM * DIM;
  const size_t SZT = (size_t)L * DIM;

  // workspace (bf16): WT[4] | xb | attn | qraw | kraw | vraw | vt
  // (attn placed between xb and qraw so unguarded A-tile staging overruns
  //  from gemm_qkv (A=xb) and gemm_out (A=attn) land in allocated memory;
  //  kraw's unguarded last-tile K reads land in vraw — kept allocated even
  //  though r14's fused V-path no longer writes it)
  u16* wt   = (u16*)d_ws;
  u16* xb   = wt + 4 * SZW;
  u16* attn = xb + SZT;
  u16* qraw = attn + SZT;
  u16* kraw = qraw + SZT;
  u16* vraw = kraw + SZT;
  u16* vtb  = vraw + SZT;
  (void)vraw;

  const int mtiles = (L + 127) / 128;

  transpose4<<<dim3(48, 48, 4), dim3(32, 8), 0, stream>>>(Wq, Wk, Wv, Wo, wt);
  cast_f32_bf16<<<(int)((SZT / 4 + 255) / 256), 256, 0, stream>>>(x, xb, (int)(SZT / 4));
  // zero vtb so the [L, Lpad) key-pad reads as 0 (was transpose_v's zero-pad)
  hipMemsetAsync(vtb, 0, (size_t)DIM * Lpad * sizeof(u16), stream);
  gemm_qkv<<<dim3(mtiles, 12, 3), 256, 0, stream>>>(
      xb, wt, bq, bk, bv, qraw, kraw, vtb, L, SZW, Lpad);
  rmsrope<<<dim3(L), 256, 0, stream>>>(qraw, kraw, gq, gk, freqs, gsz);
  attn_mfma<<<dim3((L + 127) / 128, 12), 256, 0, stream>>>(qraw, kraw, vtb, attn, seq_lens, L, Lpad);
  gemm_out<<<dim3(mtiles, 12), 256, 0, stream>>>(attn, wt + 3 * SZW, bo, out, L);
}

// Round 15
// 538.927 us; speedup vs baseline: 1.0315x; 1.0315x over previous
//
#include <hip/hip_runtime.h>

typedef unsigned short u16;
typedef unsigned int   u32;
typedef short bf16x8 __attribute__((ext_vector_type(8)));
typedef float f32x4  __attribute__((ext_vector_type(4)));

__device__ __forceinline__ float b2f(u16 u){ return __uint_as_float(((u32)u) << 16); }
__device__ __forceinline__ u16 f2bf(float f){
  u32 u = __float_as_uint(f);
  return (u16)((u + 0x7fffu + ((u >> 16) & 1u)) >> 16);  // RNE
}

// async global->LDS, 16B per lane, wave-uniform LDS base + lane*16
__device__ __forceinline__ void gload16(const u16* g, u16* l) {
  __builtin_amdgcn_global_load_lds(
      (const __attribute__((address_space(1))) unsigned int*)(g),
      (__attribute__((address_space(3))) unsigned int*)(l), 16, 0, 0);
}

// ---------------------------------------------------------------------------
// Transpose+cast four fp32 1536x1536 weights into bf16 WT[n][k]=W[k][n].
// ---------------------------------------------------------------------------
__global__ __launch_bounds__(256) void transpose4(
    const float* __restrict__ Wq, const float* __restrict__ Wk,
    const float* __restrict__ Wv, const float* __restrict__ Wo, u16* __restrict__ wt)
{
  __shared__ float tile[32][33];
  const float* src = blockIdx.z == 0 ? Wq : blockIdx.z == 1 ? Wk : blockIdx.z == 2 ? Wv : Wo;
  u16* dst = wt + (size_t)blockIdx.z * 1536 * 1536;
  const int bx = blockIdx.x * 32, by = blockIdx.y * 32;
  const int tx = threadIdx.x, ty = threadIdx.y;  // 32 x 8
#pragma unroll
  for (int i = 0; i < 32; i += 8)
    tile[ty + i][tx] = src[(size_t)(by + ty + i) * 1536 + bx + tx];
  __syncthreads();
#pragma unroll
  for (int i = 0; i < 32; i += 8)
    dst[(size_t)(bx + ty + i) * 1536 + by + tx] = f2bf(tile[tx][ty + i]);
}

// fp32 -> bf16 cast for x.
__global__ __launch_bounds__(256) void cast_f32_bf16(
    const float* __restrict__ src, u16* __restrict__ dst, int n4)
{
  int i = blockIdx.x * 256 + threadIdx.x;
  if (i < n4) {
    float4 f = ((const float4*)src)[i];
    ushort4 o;
    o.x = f2bf(f.x); o.y = f2bf(f.y); o.z = f2bf(f.z); o.w = f2bf(f.w);
    ((ushort4*)dst)[i] = o;
  }
}

// ---------------------------------------------------------------------------
// bf16 transpose: src[L][1536] -> dst[1536][Lpad], zero-padded keys >= L.
// [r15: restored — r14's fused transposed-V epilogue was net-negative:
//  per-lane 8B scatter stores cost more than this LDS-coalesced pass]
// ---------------------------------------------------------------------------
__global__ __launch_bounds__(256) void transpose_v(
    const u16* __restrict__ src, u16* __restrict__ dst, int L, int Lpad)
{
  __shared__ u16 tile[64][72];
  const int kb = blockIdx.x * 64, c0 = blockIdx.y * 64;
  const int tid = threadIdx.x;
#pragma unroll
  for (int i = 0; i < 2; i++) {
    int slot = tid + i * 256;
    int row = slot >> 3, oct = slot & 7;
    bf16x8 z = {0, 0, 0, 0, 0, 0, 0, 0};
    int key = kb + row;
    if (key < L) z = *(const bf16x8*)(src + (size_t)key * 1536 + c0 + oct * 8);
    *(bf16x8*)&tile[row][oct * 8] = z;
  }
  __syncthreads();
#pragma unroll
  for (int i = 0; i < 2; i++) {
    int slot = tid + i * 256;
    int d = slot >> 3, oct = slot & 7;
    bf16x8 z;
#pragma unroll
    for (int j = 0; j < 8; j++) z[j] = (short)tile[oct * 8 + j][d];
    *(bf16x8*)(dst + (size_t)(c0 + d) * Lpad + kb + oct * 8) = z;
  }
}

// ---------------------------------------------------------------------------
// GEMM core: C[M][1536] = A @ BT^T + bias. bf16 MFMA, fp32 acc.
// 128x128 tile, 4 waves 2x2, 4x4 mfma 16x16x32.  [frozen r4: ~420 TF,
// shape-limited per m102 curve]
// ---------------------------------------------------------------------------
template<bool F32OUT>
__device__ __forceinline__ void gemm_core(
    const u16* __restrict__ A, const u16* __restrict__ BT,
    const float* __restrict__ bias, void* __restrict__ Cv, int M,
    int m0, int n0)
{
  __shared__ u16 As[2][128][32];
  __shared__ u16 Bs[2][128][32];
  const int tid = threadIdx.x;
  const int wave = tid >> 6, lane = tid & 63;
  const int wm = (wave & 1) * 64, wn = (wave >> 1) * 64;
  const int l16 = lane & 15, quad = lane >> 4;

  // per-lane staging sources (ks = 0); each wave owns a 32-row strip.
  const int srow = lane >> 2, scol = (lane & 3) * 8;
  const u16* ap0 = A  + (size_t)(m0 + wave * 32 + srow) * 1536 + scol;
  const u16* ap1 = ap0 + (size_t)16 * 1536;
  const u16* bp0 = BT + (size_t)(n0 + wave * 32 + srow) * 1536 + scol;
  const u16* bp1 = bp0 + (size_t)16 * 1536;

#define STAGE_GEMM(curb) do { \
    gload16(ap0, &As[curb][wave * 32][0]); \
    gload16(ap1, &As[curb][wave * 32 + 16][0]); \
    gload16(bp0, &Bs[curb][wave * 32][0]); \
    gload16(bp1, &Bs[curb][wave * 32 + 16][0]); \
    ap0 += 32; ap1 += 32; bp0 += 32; bp1 += 32; } while (0)

  f32x4 acc[4][4] = {};
  STAGE_GEMM(0);
  for (int ks = 0; ks < 48; ks++) {
    const int cur = ks & 1;
    if (ks + 1 < 48) {
      STAGE_GEMM(cur ^ 1);
      asm volatile("s_waitcnt vmcnt(4)" ::: "memory");   // ks's 4 loads landed
    } else {
      asm volatile("s_waitcnt vmcnt(0)" ::: "memory");
    }
    __builtin_amdgcn_s_barrier();          // all waves: tile ks visible
    __builtin_amdgcn_sched_barrier(0);     // don't hoist ds_reads above barrier
    bf16x8 af[4], bfr[4];
#pragma unroll
    for (int mt = 0; mt < 4; mt++) af[mt] = *(const bf16x8*)&As[cur][wm + mt * 16 + l16][quad * 8];
#pragma unroll
    for (int nt = 0; nt < 4; nt++) bfr[nt] = *(const bf16x8*)&Bs[cur][wn + nt * 16 + l16][quad * 8];
#pragma unroll
    for (int mt = 0; mt < 4; mt++)
#pragma unroll
      for (int nt = 0; nt < 4; nt++)
        acc[mt][nt] = __builtin_amdgcn_mfma_f32_16x16x32_bf16(af[mt], bfr[nt], acc[mt][nt], 0, 0, 0);
    __builtin_amdgcn_s_barrier();          // all reads of buf[cur] done
  }
#undef STAGE_GEMM

#pragma unroll
  for (int nt = 0; nt < 4; nt++) {
    int col = n0 + wn + nt * 16 + l16;
    float bv = bias[col];
#pragma unroll
    for (int mt = 0; mt < 4; mt++) {
      int rowb = m0 + wm + mt * 16 + quad * 4;
#pragma unroll
      for (int r = 0; r < 4; r++) {
        int row = rowb + r;
        if (row < M) {
          float val = acc[mt][nt][r] + bv;
          if (F32OUT) ((float*)Cv)[(size_t)row * 1536 + col] = val;
          else        ((u16*)Cv)[(size_t)row * 1536 + col] = f2bf(val);
        }
      }
    }
  }
}

// Fused Q/K/V projection: blockIdx.z selects weight/bias/output.
__global__ __launch_bounds__(256) void gemm_qkv(
    const u16* __restrict__ A, const u16* __restrict__ wt,
    const float* __restrict__ bq, const float* __restrict__ bk, const float* __restrict__ bv,
    u16* __restrict__ outbase, int M, size_t SZW, size_t SZT)
{
  const int z = blockIdx.z;
  const u16* BT = wt + (size_t)z * SZW;
  const float* bias = z == 0 ? bq : z == 1 ? bk : bv;
  u16* C = outbase + (size_t)z * SZT;
  gemm_core<false>(A, BT, bias, C, M, blockIdx.x * 128, blockIdx.y * 128);
}

__global__ __launch_bounds__(256) void gemm_out(
    const u16* __restrict__ A, const u16* __restrict__ BT,
    const float* __restrict__ bias, float* __restrict__ C, int M)
{
  gemm_core<true>(A, BT, bias, C, M, blockIdx.x * 128, blockIdx.y * 128);
}

// ---------------------------------------------------------------------------
// In-place RMSNorm (dim 1536) + per-head RoPE on bf16 q/k; fp32 gains/freqs.
// r10: q additionally pre-scaled by SC = (1/sqrt(128))*log2(e) — qraw's only
// consumer is attn's Q (rope is linear, so rot(SC*q) = SC*rot(q)).
// ---------------------------------------------------------------------------
__global__ __launch_bounds__(256) void rmsrope(
    u16* __restrict__ qb, u16* __restrict__ kb,
    const float* __restrict__ gq, const float* __restrict__ gk,
    const float* __restrict__ freqs, const int* __restrict__ gsz)
{
  const int s = blockIdx.x, tid = threadIdx.x;
  const size_t base = (size_t)s * 1536;
  float qv[6], kv[6];
  float sq = 0.f, sk = 0.f;
#pragma unroll
  for (int i = 0; i < 6; i++) {
    float a = b2f(qb[base + tid * 6 + i]); qv[i] = a; sq += a * a;
    float b = b2f(kb[base + tid * 6 + i]); kv[i] = b; sk += b * b;
  }
#pragma unroll
  for (int d2 = 1; d2 < 64; d2 <<= 1) { sq += __shfl_xor(sq, d2); sk += __shfl_xor(sk, d2); }
  __shared__ float red[8];
  const int wave = tid >> 6, lane = tid & 63;
  if (lane == 0) { red[wave] = sq; red[4 + wave] = sk; }
  __syncthreads();
  sq = red[0] + red[1] + red[2] + red[3];
  sk = red[4] + red[5] + red[6] + red[7];
  const float rq = rsqrtf(sq * (1.f / 1536.f) + 1e-6f) * 0.12752551286084934f;  // * SC
  const float rk = rsqrtf(sk * (1.f / 1536.f) + 1e-6f);
  const int F = gsz[0], H = gsz[1], W = gsz[2];
  const int sl = F * H * W;
  const bool rope = s < sl;
  int pf = 0, ph = 0, pw = 0;
  if (rope) { pf = s / (H * W); int rr = s - pf * (H * W); ph = rr / W; pw = rr - ph * W; }
#pragma unroll
  for (int pp = 0; pp < 3; pp++) {
    const int j0 = tid * 6 + pp * 2;
    float qre = qv[pp * 2]     * rq * gq[j0];
    float qim = qv[pp * 2 + 1] * rq * gq[j0 + 1];
    float kre = kv[pp * 2]     * rk * gk[j0];
    float kim = kv[pp * 2 + 1] * rk * gk[j0 + 1];
    if (rope) {
      const int ti = (j0 & 127) >> 1;
      const int pos = ti < 22 ? pf : (ti < 43 ? ph : pw);
      const float ang = freqs[pos * 64 + ti];
      const float cs = cosf(ang), sn = sinf(ang);
      float t1 = qre * cs - qim * sn; qim = qre * sn + qim * cs; qre = t1;
      float t2 = kre * cs - kim * sn; kim = kre * sn + kim * cs; kre = t2;
    }
    qb[base + j0] = f2bf(qre); qb[base + j0 + 1] = f2bf(qim);
    kb[base + j0] = f2bf(kre); kb[base + j0 + 1] = f2bf(kim);
  }
}

// ---------------------------------------------------------------------------
// MFMA flash attention, 64-key tiles, register-double-buffered K/V staging.
// Block = 4 waves = 128 q rows (32/wave, two 16-row fragments), one head.
// Frozen at the r8/r13 optimum (latency-bound on the QK->softmax->PV
// dependent chain at 2 waves/SIMD; occupancy/VALU/fusion levers all
// measured-closed r5/r9/r10/r14).
// ---------------------------------------------------------------------------
__global__ __launch_bounds__(256, 2) void attn_mfma(
    const u16* __restrict__ q, const u16* __restrict__ k, const u16* __restrict__ vt,
    u16* __restrict__ o, const int* __restrict__ seq_lens, int L, int Lpad)
{
  __shared__ u16 Ks[64][136];    // K rows [key][d], pad 8
  __shared__ u16 Vs[128][72];    // V^T [d][key], pad 8
  __shared__ u16 Pl[4][32][72];  // per-wave P [q][key], pad 8
  const int tid = threadIdx.x, wave = tid >> 6, lane = tid & 63;
  const int l16 = lane & 15, quad = lane >> 4;
  const int h = blockIdx.y;
  const int seqlen = seq_lens[0];
  const int q0 = blockIdx.x * 128 + wave * 32;

  // staging coordinates (per thread, fixed)
  int krow[4], kcol[4], vd[4], voct[4];
#pragma unroll
  for (int i = 0; i < 4; i++) {
    int slot = tid + i * 256;
    krow[i] = slot >> 4; kcol[i] = (slot & 15) * 8;
    vd[i]   = slot >> 3; voct[i] = (slot & 7) * 8;
  }
  const u16* kp  = k + h * 128;
  const u16* vtp = vt + (size_t)h * 128 * Lpad;
  // incrementing prefetch pointers (advance by one 64-key tile per iteration)
  const u16* kptr[4]; const u16* vptr[4];
#pragma unroll
  for (int i = 0; i < 4; i++) {
    kptr[i] = kp + (size_t)krow[i] * 1536 + kcol[i];
    vptr[i] = vtp + (size_t)vd[i] * Lpad + voct[i];
  }

  // Q fragments for both 16-row groups (already scaled by SC in rmsrope)
  bf16x8 Qf[2][4];
#pragma unroll
  for (int qg = 0; qg < 2; qg++) {
    int qr = q0 + qg * 16 + l16;
#pragma unroll
    for (int ds = 0; ds < 4; ds++) {
      bf16x8 z = {0, 0, 0, 0, 0, 0, 0, 0};
      if (qr < L)
        z = *(const bf16x8*)(q + (size_t)qr * 1536 + h * 128 + ds * 32 + quad * 8);
      Qf[qg][ds] = z;
    }
  }
  // constant ones B-fragment: n-col 0 (lanes with l16==0) = bf16 1.0
  bf16x8 ovf = {0, 0, 0, 0, 0, 0, 0, 0};
  if (l16 == 0) {
#pragma unroll
    for (int j = 0; j < 8; j++) ovf[j] = (short)0x3F80;
  }
  f32x4 accO[2][8] = {};
  f32x4 accL[2] = {};
  float m_i[2] = {-1e30f, -1e30f};

  const int ntile = (seqlen + 63) >> 6;
  bf16x8 kpre[4], vpre[4];
  // prefetch tile 0 (unguarded: OOR rows land in adjacent allocated buffer)
#pragma unroll
  for (int i = 0; i < 4; i++) {
    kpre[i] = *(const bf16x8*)kptr[i];
    vpre[i] = *(const bf16x8*)vptr[i];
  }

  for (int t = 0; t < ntile; t++) {
    const int kb = t * 64;
    // readers-done barrier: raw s_barrier — no vmcnt/lgkm drain needed (all
    // ds_reads of tile t-1 were consumed by MFMAs). sched_barrier fences keep
    // the staging ds_writes below it (rule #18).
    __builtin_amdgcn_sched_barrier(0);
    __builtin_amdgcn_s_barrier();
    __builtin_amdgcn_sched_barrier(0);
#pragma unroll
    for (int i = 0; i < 4; i++) {
      *(bf16x8*)&Ks[krow[i]][kcol[i]] = kpre[i];
      *(bf16x8*)&Vs[vd[i]][voct[i]]   = vpre[i];
    }
    __syncthreads();   // staging visible (full drain: ds_writes must land)
    if (t + 1 < ntile) {
#pragma unroll
      for (int i = 0; i < 4; i++) {
        kptr[i] += (size_t)64 * 1536;
        vptr[i] += 64;
        kpre[i] = *(const bf16x8*)kptr[i];
        vpre[i] = *(const bf16x8*)vptr[i];
      }
    }

    // S^T: four 16(key)x16(q) tiles over d=128, both q-groups per K fragment
    const bool full = (kb + 64 <= seqlen);
    float sv[2][16];
    float tmax[2] = {-1e30f, -1e30f};
    __builtin_amdgcn_s_setprio(1);
#pragma unroll
    for (int kt = 0; kt < 4; kt++) {
      f32x4 a0 = {0.f, 0.f, 0.f, 0.f};
      f32x4 a1 = {0.f, 0.f, 0.f, 0.f};
#pragma unroll
      for (int ds = 0; ds < 4; ds++) {
        bf16x8 kf = *(const bf16x8*)&Ks[kt * 16 + l16][ds * 32 + quad * 8];
        a0 = __builtin_amdgcn_mfma_f32_16x16x32_bf16(kf, Qf[0][ds], a0, 0, 0, 0);
        a1 = __builtin_amdgcn_mfma_f32_16x16x32_bf16(kf, Qf[1][ds], a1, 0, 0, 0);
      }
      if (full) {
#pragma unroll
        for (int r = 0; r < 4; r++) { sv[0][kt * 4 + r] = a0[r]; sv[1][kt * 4 + r] = a1[r]; }
        // tree max (max3-fusable): 2 ops to reduce 4, 1 to accumulate
        tmax[0] = fmaxf(tmax[0], fmaxf(fmaxf(a0[0], a0[1]), fmaxf(a0[2], a0[3])));
        tmax[1] = fmaxf(tmax[1], fmaxf(fmaxf(a1[0], a1[1]), fmaxf(a1[2], a1[3])));
      } else {
#pragma unroll
        for (int r = 0; r < 4; r++) {
          int key = kb + kt * 16 + quad * 4 + r;
          float s0 = (key < seqlen) ? a0[r] : -1e30f;
          float s1 = (key < seqlen) ? a1[r] : -1e30f;
          sv[0][kt * 4 + r] = s0; tmax[0] = fmaxf(tmax[0], s0);
          sv[1][kt * 4 + r] = s1; tmax[1] = fmaxf(tmax[1], s1);
        }
      }
    }
    __builtin_amdgcn_s_setprio(0);
    bool resc[2];
    float alpha[2] = {1.f, 1.f};
#pragma unroll
    for (int qg = 0; qg < 2; qg++) {
      float tm = tmax[qg];
      tm = fmaxf(tm, __shfl_xor(tm, 16));
      tm = fmaxf(tm, __shfl_xor(tm, 32));
      resc[qg] = !__all(tm - m_i[qg] <= 8.f);
      float mnew = m_i[qg];
      if (resc[qg]) {                       // wave-uniform branch
        mnew = fmaxf(m_i[qg], tm);
        alpha[qg] = exp2f(m_i[qg] - mnew);
      }
      // pair-pack truncated-bf16 P: (hi16(pb)<<16)|hi16(pa) per pair
      u32 pw[8];
#pragma unroll
      for (int i2 = 0; i2 < 8; i2++) {
        float pa = exp2f(sv[qg][i2 * 2]     - mnew);
        float pb = exp2f(sv[qg][i2 * 2 + 1] - mnew);
        pw[i2] = (__float_as_uint(pb) & 0xffff0000u) | (__float_as_uint(pa) >> 16);
      }
      m_i[qg] = mnew;
#pragma unroll
      for (int kt = 0; kt < 4; kt++) {
        uint2 w2 = { pw[kt * 2], pw[kt * 2 + 1] };
        *(uint2*)&Pl[wave][qg * 16 + l16][kt * 16 + quad * 4] = w2;
      }
    }
#pragma unroll
    for (int qg = 0; qg < 2; qg++) {
      if (resc[qg]) {                       // wave-uniform: usually skipped
        float ar[4];
#pragma unroll
        for (int r = 0; r < 4; r++) ar[r] = __shfl(alpha[qg], quad * 4 + r);
#pragma unroll
        for (int dt = 0; dt < 8; dt++)
#pragma unroll
          for (int r = 0; r < 4; r++) accO[qg][dt][r] *= ar[r];
#pragma unroll
        for (int r = 0; r < 4; r++) accL[qg][r] *= ar[r];
      }
    }
    bf16x8 pf00 = *(const bf16x8*)&Pl[wave][l16][quad * 8];
    bf16x8 pf01 = *(const bf16x8*)&Pl[wave][l16][32 + quad * 8];
    bf16x8 pf10 = *(const bf16x8*)&Pl[wave][16 + l16][quad * 8];
    bf16x8 pf11 = *(const bf16x8*)&Pl[wave][16 + l16][32 + quad * 8];
    __builtin_amdgcn_s_setprio(1);
#pragma unroll
    for (int dt = 0; dt < 8; dt++) {
      bf16x8 vf0 = *(const bf16x8*)&Vs[dt * 16 + l16][quad * 8];
      bf16x8 vf1 = *(const bf16x8*)&Vs[dt * 16 + l16][32 + quad * 8];
      accO[0][dt] = __builtin_amdgcn_mfma_f32_16x16x32_bf16(pf00, vf0, accO[0][dt], 0, 0, 0);
      accO[0][dt] = __builtin_amdgcn_mfma_f32_16x16x32_bf16(pf01, vf1, accO[0][dt], 0, 0, 0);
      accO[1][dt] = __builtin_amdgcn_mfma_f32_16x16x32_bf16(pf10, vf0, accO[1][dt], 0, 0, 0);
      accO[1][dt] = __builtin_amdgcn_mfma_f32_16x16x32_bf16(pf11, vf1, accO[1][dt], 0, 0, 0);
    }
    // l accumulation: D[q][0] += sum_k P[q][k] * 1  (n-col 0 only)
    accL[0] = __builtin_amdgcn_mfma_f32_16x16x32_bf16(pf00, ovf, accL[0], 0, 0, 0);
    accL[0] = __builtin_amdgcn_mfma_f32_16x16x32_bf16(pf01, ovf, accL[0], 0, 0, 0);
    accL[1] = __builtin_amdgcn_mfma_f32_16x16x32_bf16(pf10, ovf, accL[1], 0, 0, 0);
    accL[1] = __builtin_amdgcn_mfma_f32_16x16x32_bf16(pf11, ovf, accL[1], 0, 0, 0);
    __builtin_amdgcn_s_setprio(0);
  }
  // epilogue: l(q=quad*4+r) = accL[qg][r] at lane l16==0 of this quad
#pragma unroll
  for (int qg = 0; qg < 2; qg++) {
    float linv[4];
#pragma unroll
    for (int r = 0; r < 4; r++) linv[r] = 1.f / __shfl(accL[qg][r], quad << 4);
#pragma unroll
    for (int r = 0; r < 4; r++) {
      int qr = q0 + qg * 16 + quad * 4 + r;
      if (qr < L) {
#pragma unroll
        for (int dt = 0; dt < 8; dt++)
          o[(size_t)qr * 1536 + h * 128 + dt * 16 + l16] = f2bf(accO[qg][dt][r] * linv[r]);
      }
    }
  }
}

// ---------------------------------------------------------------------------
extern "C" void kernel_launch(void* const* d_in, const int* in_sizes, int n_in,
                              void* d_out, int out_size, void* d_ws, size_t ws_size,
                              hipStream_t stream) {
  const float* x      = (const float*)d_in[0];
  const int* seq_lens = (const int*)d_in[1];
  const int* gsz      = (const int*)d_in[2];
  const float* freqs  = (const float*)d_in[3];
  const float* Wq     = (const float*)d_in[4];
  const float* bq     = (const float*)d_in[5];
  const float* Wk     = (const float*)d_in[6];
  const float* bk     = (const float*)d_in[7];
  const float* Wv     = (const float*)d_in[8];
  const float* bv     = (const float*)d_in[9];
  const float* Wo     = (const float*)d_in[10];
  const float* bo     = (const float*)d_in[11];
  const float* gq     = (const float*)d_in[12];
  const float* gk     = (const float*)d_in[13];
  float* out = (float*)d_out;   // fp32 output (proven round 5)

  const int DIM = 1536;
  const int L = in_sizes[0] / DIM;              // 5000
  const int Lpad = ((L + 63) / 64) * 64;        // 5056
  const size_t SZW = (size_t)DIM * DIM;
  const size_t SZT = (size_t)L * DIM;

  // workspace (bf16): WT[4] | xb | attn | qraw | kraw | vraw | vt
  // (attn placed between xb and qraw so unguarded A-tile staging overruns
  //  from gemm_qkv (A=xb) and gemm_out (A=attn) land in allocated memory;
  //  kraw's unguarded last-tile K reads land in vraw)
  u16* wt   = (u16*)d_ws;
  u16* xb   = wt + 4 * SZW;
  u16* attn = xb + SZT;
  u16* qraw = attn + SZT;
  u16* kraw = qraw + SZT;
  u16* vraw = kraw + SZT;
  u16* vtb  = vraw + SZT;

  const int mtiles = (L + 127) / 128;

  transpose4<<<dim3(48, 48, 4), dim3(32, 8), 0, stream>>>(Wq, Wk, Wv, Wo, wt);
  cast_f32_bf16<<<(int)((SZT / 4 + 255) / 256), 256, 0, stream>>>(x, xb, (int)(SZT / 4));
  gemm_qkv<<<dim3(mtiles, 12, 3), 256, 0, stream>>>(xb, wt, bq, bk, bv, qraw, L, SZW, SZT);
  rmsrope<<<dim3(L), 256, 0, stream>>>(qraw, kraw, gq, gk, freqs, gsz);
  transpose_v<<<dim3((L + 63) / 64, DIM / 64), 256, 0, stream>>>(vraw, vtb, L, Lpad);
  attn_mfma<<<dim3((L + 127) / 128, 12), 256, 0, stream>>>(qraw, kraw, vtb, attn, seq_lens, L, Lpad);
  gemm_out<<<dim3(mtiles, 12), 256, 0, stream>>>(attn, wt + 3 * SZW, bo, out, L);
}

// Round 18
// 532.336 us; speedup vs baseline: 1.0443x; 1.0124x over previous
//
#include <hip/hip_runtime.h>

typedef unsigned short u16;
typedef unsigned int   u32;
typedef short bf16x8 __attribute__((ext_vector_type(8)));
typedef float f32x4  __attribute__((ext_vector_type(4)));

__device__ __forceinline__ float b2f(u16 u){ return __uint_as_float(((u32)u) << 16); }
__device__ __forceinline__ u16 f2bf(float f){
  u32 u = __float_as_uint(f);
  return (u16)((u + 0x7fffu + ((u >> 16) & 1u)) >> 16);  // RNE
}

// async global->LDS, 16B per lane, wave-uniform LDS base + lane*16
__device__ __forceinline__ void gload16(const u16* g, u16* l) {
  __builtin_amdgcn_global_load_lds(
      (const __attribute__((address_space(1))) unsigned int*)(g),
      (__attribute__((address_space(3))) unsigned int*)(l), 16, 0, 0);
}

// ---------------------------------------------------------------------------
// Transpose+cast four fp32 1536x1536 weights into bf16 WT[n][k]=W[k][n].
// ---------------------------------------------------------------------------
__global__ __launch_bounds__(256) void transpose4(
    const float* __restrict__ Wq, const float* __restrict__ Wk,
    const float* __restrict__ Wv, const float* __restrict__ Wo, u16* __restrict__ wt)
{
  __shared__ float tile[32][33];
  const float* src = blockIdx.z == 0 ? Wq : blockIdx.z == 1 ? Wk : blockIdx.z == 2 ? Wv : Wo;
  u16* dst = wt + (size_t)blockIdx.z * 1536 * 1536;
  const int bx = blockIdx.x * 32, by = blockIdx.y * 32;
  const int tx = threadIdx.x, ty = threadIdx.y;  // 32 x 8
#pragma unroll
  for (int i = 0; i < 32; i += 8)
    tile[ty + i][tx] = src[(size_t)(by + ty + i) * 1536 + bx + tx];
  __syncthreads();
#pragma unroll
  for (int i = 0; i < 32; i += 8)
    dst[(size_t)(bx + ty + i) * 1536 + by + tx] = f2bf(tile[tx][ty + i]);
}

// fp32 -> bf16 cast for x.
__global__ __launch_bounds__(256) void cast_f32_bf16(
    const float* __restrict__ src, u16* __restrict__ dst, int n4)
{
  int i = blockIdx.x * 256 + threadIdx.x;
  if (i < n4) {
    float4 f = ((const float4*)src)[i];
    ushort4 o;
    o.x = f2bf(f.x); o.y = f2bf(f.y); o.z = f2bf(f.z); o.w = f2bf(f.w);
    ((ushort4*)dst)[i] = o;
  }
}

// ---------------------------------------------------------------------------
// bf16 transpose: src[L][1536] -> dst[1536][Lpad], zero-padded keys >= L.
// ---------------------------------------------------------------------------
__global__ __launch_bounds__(256) void transpose_v(
    const u16* __restrict__ src, u16* __restrict__ dst, int L, int Lpad)
{
  __shared__ u16 tile[64][72];
  const int kb = blockIdx.x * 64, c0 = blockIdx.y * 64;
  const int tid = threadIdx.x;
#pragma unroll
  for (int i = 0; i < 2; i++) {
    int slot = tid + i * 256;
    int row = slot >> 3, oct = slot & 7;
    bf16x8 z = {0, 0, 0, 0, 0, 0, 0, 0};
    int key = kb + row;
    if (key < L) z = *(const bf16x8*)(src + (size_t)key * 1536 + c0 + oct * 8);
    *(bf16x8*)&tile[row][oct * 8] = z;
  }
  __syncthreads();
#pragma unroll
  for (int i = 0; i < 2; i++) {
    int slot = tid + i * 256;
    int d = slot >> 3, oct = slot & 7;
    bf16x8 z;
#pragma unroll
    for (int j = 0; j < 8; j++) z[j] = (short)tile[oct * 8 + j][d];
    *(bf16x8*)(dst + (size_t)(c0 + d) * Lpad + kb + oct * 8) = z;
  }
}

// ---------------------------------------------------------------------------
// GEMM core: C[M][1536] = A @ BT^T + bias. bf16 MFMA, fp32 acc.
// 128x128 tile, 4 waves 2x2, 4x4 mfma 16x16x32.
// r16: 2-DEEP PREFETCH — 3 LDS buffers (48KB, still 3 blocks/CU; m132's
// cliff is at 64KB), stage tile ks+2 AFTER the compute barrier. Loads now
// have two compute-phases (~300+ cyc) to land vs one (~80-160 cyc) before,
// covering the ~200-300cyc L2-resident latency so vmcnt(4) finds its
// target already complete. vmcnt audit: prologue 8 outstanding (b0,b1);
// steady wait(4) retires exactly tile ks; tail ks+1==48 -> wait(0);
// buffer (ks+2)%3 was last read two barrier-pairs ago — race-free.
// ---------------------------------------------------------------------------
template<bool F32OUT>
__device__ __forceinline__ void gemm_core(
    const u16* __restrict__ A, const u16* __restrict__ BT,
    const float* __restrict__ bias, void* __restrict__ Cv, int M,
    int m0, int n0)
{
  __shared__ u16 As[3][128][32];
  __shared__ u16 Bs[3][128][32];
  const int tid = threadIdx.x;
  const int wave = tid >> 6, lane = tid & 63;
  const int wm = (wave & 1) * 64, wn = (wave >> 1) * 64;
  const int l16 = lane & 15, quad = lane >> 4;

  // per-lane staging sources (ks = 0); each wave owns a 32-row strip.
  const int srow = lane >> 2, scol = (lane & 3) * 8;
  const u16* ap0 = A  + (size_t)(m0 + wave * 32 + srow) * 1536 + scol;
  const u16* ap1 = ap0 + (size_t)16 * 1536;
  const u16* bp0 = BT + (size_t)(n0 + wave * 32 + srow) * 1536 + scol;
  const u16* bp1 = bp0 + (size_t)16 * 1536;

#define STAGE_GEMM(curb) do { \
    gload16(ap0, &As[curb][wave * 32][0]); \
    gload16(ap1, &As[curb][wave * 32 + 16][0]); \
    gload16(bp0, &Bs[curb][wave * 32][0]); \
    gload16(bp1, &Bs[curb][wave * 32 + 16][0]); \
    ap0 += 32; ap1 += 32; bp0 += 32; bp1 += 32; } while (0)

  f32x4 acc[4][4] = {};
  STAGE_GEMM(0);
  STAGE_GEMM(1);
  int cur = 0;
  for (int ks = 0; ks < 48; ks++) {
    if (ks + 1 < 48) {
      asm volatile("s_waitcnt vmcnt(4)" ::: "memory");   // tile ks's 4 landed
    } else {
      asm volatile("s_waitcnt vmcnt(0)" ::: "memory");
    }
    __builtin_amdgcn_s_barrier();          // all waves: tile ks visible
    __builtin_amdgcn_sched_barrier(0);     // don't hoist ds_reads above barrier
    bf16x8 af[4], bfr[4];
#pragma unroll
    for (int mt = 0; mt < 4; mt++) af[mt] = *(const bf16x8*)&As[cur][wm + mt * 16 + l16][quad * 8];
#pragma unroll
    for (int nt = 0; nt < 4; nt++) bfr[nt] = *(const bf16x8*)&Bs[cur][wn + nt * 16 + l16][quad * 8];
#pragma unroll
    for (int mt = 0; mt < 4; mt++)
#pragma unroll
      for (int nt = 0; nt < 4; nt++)
        acc[mt][nt] = __builtin_amdgcn_mfma_f32_16x16x32_bf16(af[mt], bfr[nt], acc[mt][nt], 0, 0, 0);
    __builtin_amdgcn_s_barrier();          // all reads of buf[cur] done
    __builtin_amdgcn_sched_barrier(0);     // keep stage below the barrier
    if (ks + 2 < 48) {
      const int nxt = cur ? cur - 1 : 2;   // (cur+2) % 3
      STAGE_GEMM(nxt);
    }
    cur = (cur == 2) ? 0 : cur + 1;
  }
#undef STAGE_GEMM

#pragma unroll
  for (int nt = 0; nt < 4; nt++) {
    int col = n0 + wn + nt * 16 + l16;
    float bv = bias[col];
#pragma unroll
    for (int mt = 0; mt < 4; mt++) {
      int rowb = m0 + wm + mt * 16 + quad * 4;
#pragma unroll
      for (int r = 0; r < 4; r++) {
        int row = rowb + r;
        if (row < M) {
          float val = acc[mt][nt][r] + bv;
          if (F32OUT) ((float*)Cv)[(size_t)row * 1536 + col] = val;
          else        ((u16*)Cv)[(size_t)row * 1536 + col] = f2bf(val);
        }
      }
    }
  }
}

// Fused Q/K/V projection: blockIdx.z selects weight/bias/output.
__global__ __launch_bounds__(256) void gemm_qkv(
    const u16* __restrict__ A, const u16* __restrict__ wt,
    const float* __restrict__ bq, const float* __restrict__ bk, const float* __restrict__ bv,
    u16* __restrict__ outbase, int M, size_t SZW, size_t SZT)
{
  const int z = blockIdx.z;
  const u16* BT = wt + (size_t)z * SZW;
  const float* bias = z == 0 ? bq : z == 1 ? bk : bv;
  u16* C = outbase + (size_t)z * SZT;
  gemm_core<false>(A, BT, bias, C, M, blockIdx.x * 128, blockIdx.y * 128);
}

__global__ __launch_bounds__(256) void gemm_out(
    const u16* __restrict__ A, const u16* __restrict__ BT,
    const float* __restrict__ bias, float* __restrict__ C, int M)
{
  gemm_core<true>(A, BT, bias, C, M, blockIdx.x * 128, blockIdx.y * 128);
}

// ---------------------------------------------------------------------------
// In-place RMSNorm (dim 1536) + per-head RoPE on bf16 q/k; fp32 gains/freqs.
// r10: q additionally pre-scaled by SC = (1/sqrt(128))*log2(e) — qraw's only
// consumer is attn's Q (rope is linear, so rot(SC*q) = SC*rot(q)).
// ---------------------------------------------------------------------------
__global__ __launch_bounds__(256) void rmsrope(
    u16* __restrict__ qb, u16* __restrict__ kb,
    const float* __restrict__ gq, const float* __restrict__ gk,
    const float* __restrict__ freqs, const int* __restrict__ gsz)
{
  const int s = blockIdx.x, tid = threadIdx.x;
  const size_t base = (size_t)s * 1536;
  float qv[6], kv[6];
  float sq = 0.f, sk = 0.f;
#pragma unroll
  for (int i = 0; i < 6; i++) {
    float a = b2f(qb[base + tid * 6 + i]); qv[i] = a; sq += a * a;
    float b = b2f(kb[base + tid * 6 + i]); kv[i] = b; sk += b * b;
  }
#pragma unroll
  for (int d2 = 1; d2 < 64; d2 <<= 1) { sq += __shfl_xor(sq, d2); sk += __shfl_xor(sk, d2); }
  __shared__ float red[8];
  const int wave = tid >> 6, lane = tid & 63;
  if (lane == 0) { red[wave] = sq; red[4 + wave] = sk; }
  __syncthreads();
  sq = red[0] + red[1] + red[2] + red[3];
  sk = red[4] + red[5] + red[6] + red[7];
  const float rq = rsqrtf(sq * (1.f / 1536.f) + 1e-6f) * 0.12752551286084934f;  // * SC
  const float rk = rsqrtf(sk * (1.f / 1536.f) + 1e-6f);
  const int F = gsz[0], H = gsz[1], W = gsz[2];
  const int sl = F * H * W;
  const bool rope = s < sl;
  int pf = 0, ph = 0, pw = 0;
  if (rope) { pf = s / (H * W); int rr = s - pf * (H * W); ph = rr / W; pw = rr - ph * W; }
#pragma unroll
  for (int pp = 0; pp < 3; pp++) {
    const int j0 = tid * 6 + pp * 2;
    float qre = qv[pp * 2]     * rq * gq[j0];
    float qim = qv[pp * 2 + 1] * rq * gq[j0 + 1];
    float kre = kv[pp * 2]     * rk * gk[j0];
    float kim = kv[pp * 2 + 1] * rk * gk[j0 + 1];
    if (rope) {
      const int ti = (j0 & 127) >> 1;
      const int pos = ti < 22 ? pf : (ti < 43 ? ph : pw);
      const float ang = freqs[pos * 64 + ti];
      const float cs = cosf(ang), sn = sinf(ang);
      float t1 = qre * cs - qim * sn; qim = qre * sn + qim * cs; qre = t1;
      float t2 = kre * cs - kim * sn; kim = kre * sn + kim * cs; kre = t2;
    }
    qb[base + j0] = f2bf(qre); qb[base + j0 + 1] = f2bf(qim);
    kb[base + j0] = f2bf(kre); kb[base + j0 + 1] = f2bf(kim);
  }
}

// ---------------------------------------------------------------------------
// MFMA flash attention, 64-key tiles, register-double-buffered K/V staging.
// Block = 4 waves = 128 q rows (32/wave, two 16-row fragments), one head.
// Frozen at the r8/r13/r15 optimum (latency-bound on the QK->softmax->PV
// dependent chain at 2 waves/SIMD; occupancy/VALU/fusion levers all
// measured-closed r5/r9/r10/r14).
// ---------------------------------------------------------------------------
__global__ __launch_bounds__(256, 2) void attn_mfma(
    const u16* __restrict__ q, const u16* __restrict__ k, const u16* __restrict__ vt,
    u16* __restrict__ o, const int* __restrict__ seq_lens, int L, int Lpad)
{
  __shared__ u16 Ks[64][136];    // K rows [key][d], pad 8
  __shared__ u16 Vs[128][72];    // V^T [d][key], pad 8
  __shared__ u16 Pl[4][32][72];  // per-wave P [q][key], pad 8
  const int tid = threadIdx.x, wave = tid >> 6, lane = tid & 63;
  const int l16 = lane & 15, quad = lane >> 4;
  const int h = blockIdx.y;
  const int seqlen = seq_lens[0];
  const int q0 = blockIdx.x * 128 + wave * 32;

  // staging coordinates (per thread, fixed)
  int krow[4], kcol[4], vd[4], voct[4];
#pragma unroll
  for (int i = 0; i < 4; i++) {
    int slot = tid + i * 256;
    krow[i] = slot >> 4; kcol[i] = (slot & 15) * 8;
    vd[i]   = slot >> 3; voct[i] = (slot & 7) * 8;
  }
  const u16* kp  = k + h * 128;
  const u16* vtp = vt + (size_t)h * 128 * Lpad;
  // incrementing prefetch pointers (advance by one 64-key tile per iteration)
  const u16* kptr[4]; const u16* vptr[4];
#pragma unroll
  for (int i = 0; i < 4; i++) {
    kptr[i] = kp + (size_t)krow[i] * 1536 + kcol[i];
    vptr[i] = vtp + (size_t)vd[i] * Lpad + voct[i];
  }

  // Q fragments for both 16-row groups (already scaled by SC in rmsrope)
  bf16x8 Qf[2][4];
#pragma unroll
  for (int qg = 0; qg < 2; qg++) {
    int qr = q0 + qg * 16 + l16;
#pragma unroll
    for (int ds = 0; ds < 4; ds++) {
      bf16x8 z = {0, 0, 0, 0, 0, 0, 0, 0};
      if (qr < L)
        z = *(const bf16x8*)(q + (size_t)qr * 1536 + h * 128 + ds * 32 + quad * 8);
      Qf[qg][ds] = z;
    }
  }
  // constant ones B-fragment: n-col 0 (lanes with l16==0) = bf16 1.0
  bf16x8 ovf = {0, 0, 0, 0, 0, 0, 0, 0};
  if (l16 == 0) {
#pragma unroll
    for (int j = 0; j < 8; j++) ovf[j] = (short)0x3F80;
  }
  f32x4 accO[2][8] = {};
  f32x4 accL[2] = {};
  float m_i[2] = {-1e30f, -1e30f};

  const int ntile = (seqlen + 63) >> 6;
  bf16x8 kpre[4], vpre[4];
  // prefetch tile 0 (unguarded: OOR rows land in adjacent allocated buffer)
#pragma unroll
  for (int i = 0; i < 4; i++) {
    kpre[i] = *(const bf16x8*)kptr[i];
    vpre[i] = *(const bf16x8*)vptr[i];
  }

  for (int t = 0; t < ntile; t++) {
    const int kb = t * 64;
    // readers-done barrier: raw s_barrier — no vmcnt/lgkm drain needed (all
    // ds_reads of tile t-1 were consumed by MFMAs). sched_barrier fences keep
    // the staging ds_writes below it (rule #18).
    __builtin_amdgcn_sched_barrier(0);
    __builtin_amdgcn_s_barrier();
    __builtin_amdgcn_sched_barrier(0);
#pragma unroll
    for (int i = 0; i < 4; i++) {
      *(bf16x8*)&Ks[krow[i]][kcol[i]] = kpre[i];
      *(bf16x8*)&Vs[vd[i]][voct[i]]   = vpre[i];
    }
    __syncthreads();   // staging visible (full drain: ds_writes must land)
    if (t + 1 < ntile) {
#pragma unroll
      for (int i = 0; i < 4; i++) {
        kptr[i] += (size_t)64 * 1536;
        vptr[i] += 64;
        kpre[i] = *(const bf16x8*)kptr[i];
        vpre[i] = *(const bf16x8*)vptr[i];
      }
    }

    // S^T: four 16(key)x16(q) tiles over d=128, both q-groups per K fragment
    const bool full = (kb + 64 <= seqlen);
    float sv[2][16];
    float tmax[2] = {-1e30f, -1e30f};
    __builtin_amdgcn_s_setprio(1);
#pragma unroll
    for (int kt = 0; kt < 4; kt++) {
      f32x4 a0 = {0.f, 0.f, 0.f, 0.f};
      f32x4 a1 = {0.f, 0.f, 0.f, 0.f};
#pragma unroll
      for (int ds = 0; ds < 4; ds++) {
        bf16x8 kf = *(const bf16x8*)&Ks[kt * 16 + l16][ds * 32 + quad * 8];
        a0 = __builtin_amdgcn_mfma_f32_16x16x32_bf16(kf, Qf[0][ds], a0, 0, 0, 0);
        a1 = __builtin_amdgcn_mfma_f32_16x16x32_bf16(kf, Qf[1][ds], a1, 0, 0, 0);
      }
      if (full) {
#pragma unroll
        for (int r = 0; r < 4; r++) { sv[0][kt * 4 + r] = a0[r]; sv[1][kt * 4 + r] = a1[r]; }
        // tree max (max3-fusable): 2 ops to reduce 4, 1 to accumulate
        tmax[0] = fmaxf(tmax[0], fmaxf(fmaxf(a0[0], a0[1]), fmaxf(a0[2], a0[3])));
        tmax[1] = fmaxf(tmax[1], fmaxf(fmaxf(a1[0], a1[1]), fmaxf(a1[2], a1[3])));
      } else {
#pragma unroll
        for (int r = 0; r < 4; r++) {
          int key = kb + kt * 16 + quad * 4 + r;
          float s0 = (key < seqlen) ? a0[r] : -1e30f;
          float s1 = (key < seqlen) ? a1[r] : -1e30f;
          sv[0][kt * 4 + r] = s0; tmax[0] = fmaxf(tmax[0], s0);
          sv[1][kt * 4 + r] = s1; tmax[1] = fmaxf(tmax[1], s1);
        }
      }
    }
    __builtin_amdgcn_s_setprio(0);
    bool resc[2];
    float alpha[2] = {1.f, 1.f};
#pragma unroll
    for (int qg = 0; qg < 2; qg++) {
      float tm = tmax[qg];
      tm = fmaxf(tm, __shfl_xor(tm, 16));
      tm = fmaxf(tm, __shfl_xor(tm, 32));
      resc[qg] = !__all(tm - m_i[qg] <= 8.f);
      float mnew = m_i[qg];
      if (resc[qg]) {                       // wave-uniform branch
        mnew = fmaxf(m_i[qg], tm);
        alpha[qg] = exp2f(m_i[qg] - mnew);
      }
      // pair-pack truncated-bf16 P: (hi16(pb)<<16)|hi16(pa) per pair
      u32 pw[8];
#pragma unroll
      for (int i2 = 0; i2 < 8; i2++) {
        float pa = exp2f(sv[qg][i2 * 2]     - mnew);
        float pb = exp2f(sv[qg][i2 * 2 + 1] - mnew);
        pw[i2] = (__float_as_uint(pb) & 0xffff0000u) | (__float_as_uint(pa) >> 16);
      }
      m_i[qg] = mnew;
#pragma unroll
      for (int kt = 0; kt < 4; kt++) {
        uint2 w2 = { pw[kt * 2], pw[kt * 2 + 1] };
        *(uint2*)&Pl[wave][qg * 16 + l16][kt * 16 + quad * 4] = w2;
      }
    }
#pragma unroll
    for (int qg = 0; qg < 2; qg++) {
      if (resc[qg]) {                       // wave-uniform: usually skipped
        float ar[4];
#pragma unroll
        for (int r = 0; r < 4; r++) ar[r] = __shfl(alpha[qg], quad * 4 + r);
#pragma unroll
        for (int dt = 0; dt < 8; dt++)
#pragma unroll
          for (int r = 0; r < 4; r++) accO[qg][dt][r] *= ar[r];
#pragma unroll
        for (int r = 0; r < 4; r++) accL[qg][r] *= ar[r];
      }
    }
    bf16x8 pf00 = *(const bf16x8*)&Pl[wave][l16][quad * 8];
    bf16x8 pf01 = *(const bf16x8*)&Pl[wave][l16][32 + quad * 8];
    bf16x8 pf10 = *(const bf16x8*)&Pl[wave][16 + l16][quad * 8];
    bf16x8 pf11 = *(const bf16x8*)&Pl[wave][16 + l16][32 + quad * 8];
    __builtin_amdgcn_s_setprio(1);
#pragma unroll
    for (int dt = 0; dt < 8; dt++) {
      bf16x8 vf0 = *(const bf16x8*)&Vs[dt * 16 + l16][quad * 8];
      bf16x8 vf1 = *(const bf16x8*)&Vs[dt * 16 + l16][32 + quad * 8];
      accO[0][dt] = __builtin_amdgcn_mfma_f32_16x16x32_bf16(pf00, vf0, accO[0][dt], 0, 0, 0);
      accO[0][dt] = __builtin_amdgcn_mfma_f32_16x16x32_bf16(pf01, vf1, accO[0][dt], 0, 0, 0);
      accO[1][dt] = __builtin_amdgcn_mfma_f32_16x16x32_bf16(pf10, vf0, accO[1][dt], 0, 0, 0);
      accO[1][dt] = __builtin_amdgcn_mfma_f32_16x16x32_bf16(pf11, vf1, accO[1][dt], 0, 0, 0);
    }
    // l accumulation: D[q][0] += sum_k P[q][k] * 1  (n-col 0 only)
    accL[0] = __builtin_amdgcn_mfma_f32_16x16x32_bf16(pf00, ovf, accL[0], 0, 0, 0);
    accL[0] = __builtin_amdgcn_mfma_f32_16x16x32_bf16(pf01, ovf, accL[0], 0, 0, 0);
    accL[1] = __builtin_amdgcn_mfma_f32_16x16x32_bf16(pf10, ovf, accL[1], 0, 0, 0);
    accL[1] = __builtin_amdgcn_mfma_f32_16x16x32_bf16(pf11, ovf, accL[1], 0, 0, 0);
    __builtin_amdgcn_s_setprio(0);
  }
  // epilogue: l(q=quad*4+r) = accL[qg][r] at lane l16==0 of this quad
#pragma unroll
  for (int qg = 0; qg < 2; qg++) {
    float linv[4];
#pragma unroll
    for (int r = 0; r < 4; r++) linv[r] = 1.f / __shfl(accL[qg][r], quad << 4);
#pragma unroll
    for (int r = 0; r < 4; r++) {
      int qr = q0 + qg * 16 + quad * 4 + r;
      if (qr < L) {
#pragma unroll
        for (int dt = 0; dt < 8; dt++)
          o[(size_t)qr * 1536 + h * 128 + dt * 16 + l16] = f2bf(accO[qg][dt][r] * linv[r]);
      }
    }
  }
}

// ---------------------------------------------------------------------------
extern "C" void kernel_launch(void* const* d_in, const int* in_sizes, int n_in,
                              void* d_out, int out_size, void* d_ws, size_t ws_size,
                              hipStream_t stream) {
  const float* x      = (const float*)d_in[0];
  const int* seq_lens = (const int*)d_in[1];
  const int* gsz      = (const int*)d_in[2];
  const float* freqs  = (const float*)d_in[3];
  const float* Wq     = (const float*)d_in[4];
  const float* bq     = (const float*)d_in[5];
  const float* Wk     = (const float*)d_in[6];
  const float* bk     = (const float*)d_in[7];
  const float* Wv     = (const float*)d_in[8];
  const float* bv     = (const float*)d_in[9];
  const float* Wo     = (const float*)d_in[10];
  const float* bo     = (const float*)d_in[11];
  const float* gq     = (const float*)d_in[12];
  const float* gk     = (const float*)d_in[13];
  float* out = (float*)d_out;   // fp32 output (proven round 5)

  const int DIM = 1536;
  const int L = in_sizes[0] / DIM;              // 5000
  const int Lpad = ((L + 63) / 64) * 64;        // 5056
  const size_t SZW = (size_t)DIM * DIM;
  const size_t SZT = (size_t)L * DIM;

  // workspace (bf16): WT[4] | xb | attn | qraw | kraw | vraw | vt
  // (attn placed between xb and qraw so unguarded A-tile staging overruns
  //  from gemm_qkv (A=xb) and gemm_out (A=attn) land in allocated memory;
  //  kraw's unguarded last-tile K reads land in vraw)
  u16* wt   = (u16*)d_ws;
  u16* xb   = wt + 4 * SZW;
  u16* attn = xb + SZT;
  u16* qraw = attn + SZT;
  u16* kraw = qraw + SZT;
  u16* vraw = kraw + SZT;
  u16* vtb  = vraw + SZT;

  const int mtiles = (L + 127) / 128;

  transpose4<<<dim3(48, 48, 4), dim3(32, 8), 0, stream>>>(Wq, Wk, Wv, Wo, wt);
  cast_f32_bf16<<<(int)((SZT / 4 + 255) / 256), 256, 0, stream>>>(x, xb, (int)(SZT / 4));
  gemm_qkv<<<dim3(mtiles, 12, 3), 256, 0, stream>>>(xb, wt, bq, bk, bv, qraw, L, SZW, SZT);
  rmsrope<<<dim3(L), 256, 0, stream>>>(qraw, kraw, gq, gk, freqs, gsz);
  transpose_v<<<dim3((L + 63) / 64, DIM / 64), 256, 0, stream>>>(vraw, vtb, L, Lpad);
  attn_mfma<<<dim3((L + 127) / 128, 12), 256, 0, stream>>>(qraw, kraw, vtb, attn, seq_lens, L, Lpad);
  gemm_out<<<dim3(mtiles, 12), 256, 0, stream>>>(attn, wt + 3 * SZW, bo, out, L);
}